// Round 24
// baseline (438.266 us; speedup 1.0000x reference)
//
#include <hip/hip_runtime.h>
#include <hip/hip_bf16.h>

#define N_NODES_C 100000
#define N_EDGES_C 1600000
#define HID 128
#define OUTD 8
#define N_GRAPHS_C 128
#define SEG 8     // pool segments per graph
#define NBUCK 256 // CSR sort buckets
#define BSZ 391   // nodes per bucket
#define BCAP 8192
#define CHUNK 4096
#define EPT 16
#define GT 64     // nodes per fused-layer tile
#define GTILES ((N_NODES_C + GT - 1) / GT)  // 1563

typedef __attribute__((ext_vector_type(4))) float f4;
typedef __attribute__((ext_vector_type(8))) float f32x8;
typedef __attribute__((ext_vector_type(4))) _Float16 h4;
typedef __attribute__((ext_vector_type(8))) _Float16 f16x8;
typedef __attribute__((ext_vector_type(4))) float f32x4;

static inline size_t align_up(size_t x, size_t a) { return (x + a - 1) & ~(a - 1); }

__device__ __forceinline__ f4 h2f(h4 v) { return __builtin_convertvector(v, f4); }
__device__ __forceinline__ h4 f2h(f4 v) { return __builtin_convertvector(v, h4); }
__device__ __forceinline__ f32x8 h2f8(f16x8 v) { return __builtin_convertvector(v, f32x8); }

__global__ __launch_bounds__(256) void k_cvt(const float* __restrict__ in,
                                             _Float16* __restrict__ out) {
    int i = blockIdx.x * blockDim.x + threadIdx.x;
    f4 v = *(const f4*)(in + (size_t)i * 4);
    *(h4*)(out + (size_t)i * 4) = f2h(v);
}

// Build wT fp16 [L][2][j][k] from W_rel/W_root fp32 [L][k][j]
__global__ __launch_bounds__(128) void k_wprep(
    const float* __restrict__ W_rel, const float* __restrict__ W_root,
    _Float16* __restrict__ wT) {
    const int b = blockIdx.x;
    const int l = b >> 8;
    const int m = (b >> 7) & 1;
    const int j = b & 127;
    const int k = threadIdx.x;
    const float* W = (m == 0 ? W_rel : W_root) + (size_t)l * HID * HID;
    wT[(((size_t)l * 2 + m) * HID + j) * HID + k] = (_Float16)W[k * HID + j];
}

// ==================== CSR build: 2-pass LDS-staged bucket sort ====================

__global__ __launch_bounds__(256) void k_zeroB(int* __restrict__ b) { b[threadIdx.x] = 0; }

__global__ __launch_bounds__(256) void k_hist1(const int* __restrict__ dst,
                                               int* __restrict__ bhist) {
    __shared__ int h[NBUCK];
    h[threadIdx.x] = 0;
    __syncthreads();
    int stride = gridDim.x * blockDim.x;
    for (int e = blockIdx.x * 256 + threadIdx.x; e < N_EDGES_C; e += stride)
        atomicAdd(&h[dst[e] / BSZ], 1);
    __syncthreads();
    if (h[threadIdx.x]) atomicAdd(&bhist[threadIdx.x], h[threadIdx.x]);
}

__global__ __launch_bounds__(256) void k_bscan(const int* __restrict__ bhist,
                                               int* __restrict__ bbase,
                                               int* __restrict__ bcursor) {
    __shared__ int s[NBUCK];
    const int tid = threadIdx.x;
    int v = bhist[tid];
    s[tid] = v;
    __syncthreads();
    for (int off = 1; off < NBUCK; off <<= 1) {
        int t = (tid >= off) ? s[tid - off] : 0;
        __syncthreads();
        s[tid] += t;
        __syncthreads();
    }
    int excl = s[tid] - v;
    bbase[tid] = excl;
    bcursor[tid] = excl;
    if (tid == NBUCK - 1) bbase[NBUCK] = N_EDGES_C;
}

__global__ __launch_bounds__(256) void k_scatter1(
    const int* __restrict__ src, const int* __restrict__ dst,
    int* __restrict__ bcursor, unsigned* __restrict__ tmp) {
    __shared__ int h[NBUCK], sc[NBUCK], gb[NBUCK], lc[NBUCK];
    __shared__ unsigned lbuf[CHUNK];
    const int tid = threadIdx.x;
    const int base = blockIdx.x * CHUNK;
    h[tid] = 0; lc[tid] = 0;
    __syncthreads();
    unsigned rec[EPT]; int bk[EPT];
#pragma unroll
    for (int i = 0; i < EPT; ++i) {
        int e = base + i * 256 + tid;
        if (e < N_EDGES_C) {
            int d = dst[e];
            int b = d / BSZ;
            rec[i] = ((unsigned)src[e] << 9) | (unsigned)(d - b * BSZ);
            bk[i] = b;
            atomicAdd(&h[b], 1);
        } else bk[i] = -1;
    }
    __syncthreads();
    int v = h[tid];
    sc[tid] = v;
    __syncthreads();
    for (int off = 1; off < NBUCK; off <<= 1) {
        int t = (tid >= off) ? sc[tid - off] : 0;
        __syncthreads();
        sc[tid] += t;
        __syncthreads();
    }
    int excl = sc[tid] - v;
    gb[tid] = v ? atomicAdd(&bcursor[tid], v) : 0;
    sc[tid] = excl;
    __syncthreads();
#pragma unroll
    for (int i = 0; i < EPT; ++i) {
        if (bk[i] >= 0) {
            int p = atomicAdd(&lc[bk[i]], 1);
            lbuf[sc[bk[i]] + p] = rec[i];
        }
    }
    __syncthreads();
    const int wid = tid >> 6, lane = tid & 63;
    for (int b = wid; b < NBUCK; b += 4) {
        int n = h[b], g = gb[b], l = sc[b];
        for (int i = lane; i < n; i += 64) tmp[g + i] = lbuf[l + i];
    }
}

__global__ __launch_bounds__(256) void k_sort2(
    const unsigned* __restrict__ tmp, const int* __restrict__ bbase,
    int* __restrict__ offsets, int* __restrict__ es) {
    __shared__ int h[512], s2[512], cur[512];
    __shared__ int lbuf[BCAP];
    const int b = blockIdx.x, tid = threadIdx.x;
    const int base = bbase[b];
    const int cnt = bbase[b + 1] - base;
    h[tid] = 0; h[tid + 256] = 0;
    __syncthreads();
    for (int i = tid; i < cnt; i += 256) atomicAdd(&h[tmp[base + i] & 511], 1);
    __syncthreads();
    int v0 = h[tid], v1 = h[tid + 256];
    s2[tid] = v0; s2[tid + 256] = v1;
    __syncthreads();
    for (int off = 1; off < 512; off <<= 1) {
        int t0 = (tid >= off) ? s2[tid - off] : 0;
        int t1 = (tid + 256 >= off) ? s2[tid + 256 - off] : 0;
        __syncthreads();
        s2[tid] += t0; s2[tid + 256] += t1;
        __syncthreads();
    }
    int e0 = s2[tid] - v0, e1 = s2[tid + 256] - v1;
    cur[tid] = e0; cur[tid + 256] = e1;
    {
        int gn0 = b * BSZ + tid;
        if (tid < BSZ && gn0 < N_NODES_C) offsets[gn0] = base + e0;
        int n1 = tid + 256;
        int gn1 = b * BSZ + n1;
        if (n1 < BSZ && gn1 < N_NODES_C) offsets[gn1] = base + e1;
    }
    __syncthreads();
    for (int i = tid; i < cnt; i += 256) {
        unsigned r = tmp[base + i];
        int ld = r & 511;
        int p = atomicAdd(&cur[ld], 1);
        lbuf[p] = (int)(r >> 9);
    }
    __syncthreads();
    for (int i = tid; i < cnt; i += 256) es[base + i] = lbuf[i];
    if (b == NBUCK - 1 && tid == 0) offsets[N_NODES_C] = N_EDGES_C;
}

// ==================== fused layer ====================

// Fused gather + MFMA gemm. Block owns 64 nodes:
//  Phase 1: 16-lane groups gather-sum neighbor rows (fp32 reg acc), write fp16
//           agg directly into the swizzled LDS A-tile (no global agg buffer);
//           own-h rows staged likewise.
//  Phase 2: identical LDS-staged MFMA gemm (r21-confirmed transaction fix).
// Saves 51 MB/layer agg round-trip + a launch boundary; MFMA of resident
// blocks overlaps gather stalls of others.
__global__ __launch_bounds__(256) void k_layer_fused(
    const _Float16* __restrict__ h_in, _Float16* __restrict__ h_out,
    const int* __restrict__ offsets, const int* __restrict__ es,
    const _Float16* __restrict__ wT,   // [2][HID][HID] (j,k) for this layer
    const float* __restrict__ b_rel) {
    __shared__ _Float16 ldsA[GT * HID];  // 16 KB, seg-swizzled agg tile
    __shared__ _Float16 ldsH[GT * HID];  // 16 KB, seg-swizzled own-h tile
    const int tid = threadIdx.x;
    const int n0 = blockIdx.x * GT;

    // ---- Phase 1: gather (16 groups x 16 lanes; 4 nodes per group) ----
    {
        const int g = tid >> 4;     // 0..15
        const int gl = tid & 15;    // lane in group = channel seg
        const int c8 = gl * 8;
        for (int ni = g; ni < GT; ni += 16) {
            const int node = n0 + ni;
            const bool valid = node < N_NODES_C;
            const int beg = valid ? offsets[node] : 0;
            const int end = valid ? offsets[node + 1] : 0;
            f32x8 a0 = {0.f, 0.f, 0.f, 0.f, 0.f, 0.f, 0.f, 0.f};
            f32x8 a1 = a0, a2 = a0, a3 = a0;
            int e = beg;
            for (; e + 8 <= end; e += 8) {
                int s0 = es[e],     s1 = es[e + 1], s2 = es[e + 2], s3 = es[e + 3];
                int s4 = es[e + 4], s5 = es[e + 5], s6 = es[e + 6], s7 = es[e + 7];
                f16x8 v0 = *(const f16x8*)(h_in + (size_t)s0 * HID + c8);
                f16x8 v1 = *(const f16x8*)(h_in + (size_t)s1 * HID + c8);
                f16x8 v2 = *(const f16x8*)(h_in + (size_t)s2 * HID + c8);
                f16x8 v3 = *(const f16x8*)(h_in + (size_t)s3 * HID + c8);
                f16x8 v4 = *(const f16x8*)(h_in + (size_t)s4 * HID + c8);
                f16x8 v5 = *(const f16x8*)(h_in + (size_t)s5 * HID + c8);
                f16x8 v6 = *(const f16x8*)(h_in + (size_t)s6 * HID + c8);
                f16x8 v7 = *(const f16x8*)(h_in + (size_t)s7 * HID + c8);
                a0 += h2f8(v0); a1 += h2f8(v1); a2 += h2f8(v2); a3 += h2f8(v3);
                a0 += h2f8(v4); a1 += h2f8(v5); a2 += h2f8(v6); a3 += h2f8(v7);
            }
            for (; e + 4 <= end; e += 4) {
                int s0 = es[e], s1 = es[e + 1], s2 = es[e + 2], s3 = es[e + 3];
                f16x8 v0 = *(const f16x8*)(h_in + (size_t)s0 * HID + c8);
                f16x8 v1 = *(const f16x8*)(h_in + (size_t)s1 * HID + c8);
                f16x8 v2 = *(const f16x8*)(h_in + (size_t)s2 * HID + c8);
                f16x8 v3 = *(const f16x8*)(h_in + (size_t)s3 * HID + c8);
                a0 += h2f8(v0); a1 += h2f8(v1); a2 += h2f8(v2); a3 += h2f8(v3);
            }
            for (; e < end; ++e)
                a0 += h2f8(*(const f16x8*)(h_in + (size_t)es[e] * HID + c8));
            const f32x8 t = (a0 + a1) + (a2 + a3);
            const int sp = gl ^ (ni & 7);  // XOR seg-swizzle (matches read side)
            *(f16x8*)(ldsA + ((size_t)ni * 16 + sp) * 8) =
                __builtin_convertvector(t, f16x8);
            f16x8 hv = {0, 0, 0, 0, 0, 0, 0, 0};
            if (valid) hv = *(const f16x8*)(h_in + (size_t)node * HID + c8);
            *(f16x8*)(ldsH + ((size_t)ni * 16 + sp) * 8) = hv;
        }
    }

    // W fragments: 2 j-tiles per wave (loaded while gather completes elsewhere)
    const int lane = tid & 63;
    const int wv = tid >> 6;        // 0..3
    const int row16 = lane & 15;
    const int kg = lane >> 4;       // 0..3
    f16x8 WR[2][4], WO[2][4];
    float bb[2];
#pragma unroll
    for (int p = 0; p < 2; ++p) {
        const int j = ((2 * wv + p) << 4) + row16;
        const _Float16* wr = wT + (size_t)j * HID + (kg << 3);
        const _Float16* wo = wT + (size_t)(HID + j) * HID + (kg << 3);
#pragma unroll
        for (int s = 0; s < 4; ++s) {
            WR[p][s] = *(const f16x8*)(wr + s * 32);
            WO[p][s] = *(const f16x8*)(wo + s * 32);
        }
        bb[p] = b_rel[j];
    }
    __syncthreads();

    // ---- Phase 2: MFMA gemm on the LDS tiles ----
#pragma unroll
    for (int p = 0; p < 2; ++p) {
        const int j = ((2 * wv + p) << 4) + row16;
#pragma unroll
        for (int nt = 0; nt < 4; ++nt) {
            const int r = nt * 16 + row16;  // A-row in tile
            f16x8 fA[4], fH[4];
#pragma unroll
            for (int s = 0; s < 4; ++s) {
                const int sp = (s * 4 + kg) ^ (r & 7);
                fA[s] = *(const f16x8*)(ldsA + ((size_t)r * 16 + sp) * 8);
                fH[s] = *(const f16x8*)(ldsH + ((size_t)r * 16 + sp) * 8);
            }
            f32x4 a1 = {0.f, 0.f, 0.f, 0.f}, a2 = a1;
            a1 = __builtin_amdgcn_mfma_f32_16x16x32_f16(fA[0], WR[p][0], a1, 0, 0, 0);
            a2 = __builtin_amdgcn_mfma_f32_16x16x32_f16(fA[2], WR[p][2], a2, 0, 0, 0);
            a1 = __builtin_amdgcn_mfma_f32_16x16x32_f16(fH[0], WO[p][0], a1, 0, 0, 0);
            a2 = __builtin_amdgcn_mfma_f32_16x16x32_f16(fH[2], WO[p][2], a2, 0, 0, 0);
            a1 = __builtin_amdgcn_mfma_f32_16x16x32_f16(fA[1], WR[p][1], a1, 0, 0, 0);
            a2 = __builtin_amdgcn_mfma_f32_16x16x32_f16(fA[3], WR[p][3], a2, 0, 0, 0);
            a1 = __builtin_amdgcn_mfma_f32_16x16x32_f16(fH[1], WO[p][1], a1, 0, 0, 0);
            a2 = __builtin_amdgcn_mfma_f32_16x16x32_f16(fH[3], WO[p][3], a2, 0, 0, 0);
            const f32x4 acc = a1 + a2;
#pragma unroll
            for (int rr = 0; rr < 4; ++rr) {
                const int n = n0 + nt * 16 + (kg << 2) + rr;
                if (n < N_NODES_C)
                    h_out[(size_t)n * HID + j] = (_Float16)atanf(acc[rr] + bb[p]);
            }
        }
    }
}

// Pool stage 1: per (graph, segment) partial sums over fp16 h -> fp32 part
__global__ __launch_bounds__(256) void k_pool1(
    const _Float16* __restrict__ h, const int* __restrict__ batch,
    float* __restrict__ part) {
    __shared__ float sm[2][HID];
    const int b = blockIdx.x;
    const int g = b >> 3, s = b & (SEG - 1);
    const int j = threadIdx.x & 127;
    const int half = threadIdx.x >> 7;

    int lo = 0, hi = N_NODES_C;
    while (lo < hi) { int mid = (lo + hi) >> 1; if (batch[mid] < g) lo = mid + 1; else hi = mid; }
    int start = lo;
    hi = N_NODES_C;
    while (lo < hi) { int mid = (lo + hi) >> 1; if (batch[mid] < g + 1) lo = mid + 1; else hi = mid; }
    int end = lo;
    int len = end - start;
    int s0 = start + (int)((long long)len * s / SEG);
    int s1 = start + (int)((long long)len * (s + 1) / SEG);

    float acc = 0.f;
    for (int i = s0 + half; i < s1; i += 2) acc += (float)h[(size_t)i * HID + j];
    sm[half][j] = acc;
    __syncthreads();
    if (threadIdx.x < HID) part[(size_t)b * HID + j] = sm[0][j] + sm[1][j];
}

// Pool stage 2 + head
__global__ __launch_bounds__(128) void k_head(
    const float* __restrict__ part, const float* __restrict__ W_out,
    const float* __restrict__ b_out, float* __restrict__ out) {
    __shared__ float sf[HID];
    const int g = blockIdx.x;
    const int j = threadIdx.x;
    float v = 0.f;
    for (int s = 0; s < SEG; ++s) v += part[(size_t)(g * SEG + s) * HID + j];
    sf[j] = v;
    __syncthreads();
    if (j < OUTD) {
        float a = b_out[j];
        for (int k = 0; k < HID; ++k) a += sf[k] * W_out[k * OUTD + j];
        out[g * OUTD + j] = 1.f / (1.f + expf(-a));
    }
}

extern "C" void kernel_launch(void* const* d_in, const int* in_sizes, int n_in,
                              void* d_out, int out_size, void* d_ws, size_t ws_size,
                              hipStream_t stream) {
    const float* x      = (const float*)d_in[0];
    const int*   ei     = (const int*)d_in[1];
    const int*   src    = ei;
    const int*   dst    = ei + N_EDGES_C;
    const int*   batch  = (const int*)d_in[2];
    const float* W_rel  = (const float*)d_in[3];
    const float* b_rel  = (const float*)d_in[4];
    const float* W_root = (const float*)d_in[5];
    const float* W_out  = (const float*)d_in[6];
    const float* b_out  = (const float*)d_in[7];
    float* out = (float*)d_out;

    char* ws = (char*)d_ws;
    size_t off = 0;
    auto alloc = [&](size_t bytes) { void* p = ws + off; off = align_up(off + bytes, 256); return p; };
    _Float16* xh    = (_Float16*)alloc((size_t)N_NODES_C * HID * 2);  // x fp16; reused as h2
    _Float16* h1h   = (_Float16*)alloc((size_t)N_NODES_C * HID * 2);  // h1 fp16; reused as h3
    _Float16* wT    = (_Float16*)alloc((size_t)3 * 2 * HID * HID * 2);
    int*   offsets = (int*)alloc((size_t)(N_NODES_C + 1) * sizeof(int));
    int*   es      = (int*)alloc((size_t)N_EDGES_C * sizeof(int));
    unsigned* tmp  = (unsigned*)alloc((size_t)N_EDGES_C * sizeof(unsigned));
    int*   bhist   = (int*)alloc(NBUCK * sizeof(int));
    int*   bbase   = (int*)alloc((NBUCK + 1) * sizeof(int));
    int*   bcursor = (int*)alloc(NBUCK * sizeof(int));
    float* part    = (float*)alloc((size_t)N_GRAPHS_C * SEG * HID * sizeof(float));

    const int scat_blocks = (N_EDGES_C + CHUNK - 1) / CHUNK;  // 391
    const size_t WTL = (size_t)2 * HID * HID;

    // ---- weight prep + x -> fp16 ----
    k_wprep<<<768, 128, 0, stream>>>(W_rel, W_root, wT);
    k_cvt<<<(N_NODES_C * HID) / 4 / 256, 256, 0, stream>>>(x, xh);

    // ---- CSR build: bucket sort, all global scatter staged through LDS ----
    k_zeroB<<<1, 256, 0, stream>>>(bhist);
    k_hist1<<<1024, 256, 0, stream>>>(dst, bhist);
    k_bscan<<<1, 256, 0, stream>>>(bhist, bbase, bcursor);
    k_scatter1<<<scat_blocks, 256, 0, stream>>>(src, dst, bcursor, tmp);
    k_sort2<<<NBUCK, 256, 0, stream>>>(tmp, bbase, offsets, es);

    // ---- 3 fused GraphConv layers ----
    k_layer_fused<<<GTILES, 256, 0, stream>>>(xh,  h1h, offsets, es, wT + 0 * WTL, b_rel + 0 * HID);
    k_layer_fused<<<GTILES, 256, 0, stream>>>(h1h, xh,  offsets, es, wT + 1 * WTL, b_rel + 1 * HID);
    k_layer_fused<<<GTILES, 256, 0, stream>>>(xh,  h1h, offsets, es, wT + 2 * WTL, b_rel + 2 * HID);

    // ---- pool + head ----
    k_pool1<<<N_GRAPHS_C * SEG, 256, 0, stream>>>(h1h, batch, part);
    k_head<<<N_GRAPHS_C, 128, 0, stream>>>(part, W_out, b_out, out);
}

// Round 25
// 395.996 us; speedup vs baseline: 1.1067x; 1.1067x over previous
//
#include <hip/hip_runtime.h>
#include <hip/hip_bf16.h>

#define N_NODES_C 100000
#define N_EDGES_C 1600000
#define HID 128
#define OUTD 8
#define N_GRAPHS_C 128
#define SEG 8     // pool segments per graph
#define NBUCK 256 // CSR sort buckets
#define BSZ 391   // nodes per bucket
#define BCAP 8192
#define CHUNK 4096
#define EPT 16
#define GT 64     // nodes per gemm tile
#define GTILES ((N_NODES_C + GT - 1) / GT)  // 1563
#define GBLOCKS 512

typedef __attribute__((ext_vector_type(4))) float f4;
typedef __attribute__((ext_vector_type(8))) float f32x8;
typedef __attribute__((ext_vector_type(4))) _Float16 h4;
typedef __attribute__((ext_vector_type(8))) _Float16 f16x8;
typedef __attribute__((ext_vector_type(4))) float f32x4;

static inline size_t align_up(size_t x, size_t a) { return (x + a - 1) & ~(a - 1); }

__device__ __forceinline__ f4 h2f(h4 v) { return __builtin_convertvector(v, f4); }
__device__ __forceinline__ h4 f2h(f4 v) { return __builtin_convertvector(v, h4); }
__device__ __forceinline__ f32x8 h2f8(f16x8 v) { return __builtin_convertvector(v, f32x8); }

__global__ __launch_bounds__(256) void k_cvt(const float* __restrict__ in,
                                             _Float16* __restrict__ out) {
    int i = blockIdx.x * blockDim.x + threadIdx.x;
    f4 v = *(const f4*)(in + (size_t)i * 4);
    *(h4*)(out + (size_t)i * 4) = f2h(v);
}

// Build wT fp16 [L][2][j][k] from W_rel/W_root fp32 [L][k][j]
__global__ __launch_bounds__(128) void k_wprep(
    const float* __restrict__ W_rel, const float* __restrict__ W_root,
    _Float16* __restrict__ wT) {
    const int b = blockIdx.x;
    const int l = b >> 8;
    const int m = (b >> 7) & 1;
    const int j = b & 127;
    const int k = threadIdx.x;
    const float* W = (m == 0 ? W_rel : W_root) + (size_t)l * HID * HID;
    wT[(((size_t)l * 2 + m) * HID + j) * HID + k] = (_Float16)W[k * HID + j];
}

// ==================== CSR build: 2-pass LDS-staged bucket sort ====================

__global__ __launch_bounds__(256) void k_zeroB(int* __restrict__ b) { b[threadIdx.x] = 0; }

__global__ __launch_bounds__(256) void k_hist1(const int* __restrict__ dst,
                                               int* __restrict__ bhist) {
    __shared__ int h[NBUCK];
    h[threadIdx.x] = 0;
    __syncthreads();
    int stride = gridDim.x * blockDim.x;
    for (int e = blockIdx.x * 256 + threadIdx.x; e < N_EDGES_C; e += stride)
        atomicAdd(&h[dst[e] / BSZ], 1);
    __syncthreads();
    if (h[threadIdx.x]) atomicAdd(&bhist[threadIdx.x], h[threadIdx.x]);
}

__global__ __launch_bounds__(256) void k_bscan(const int* __restrict__ bhist,
                                               int* __restrict__ bbase,
                                               int* __restrict__ bcursor) {
    __shared__ int s[NBUCK];
    const int tid = threadIdx.x;
    int v = bhist[tid];
    s[tid] = v;
    __syncthreads();
    for (int off = 1; off < NBUCK; off <<= 1) {
        int t = (tid >= off) ? s[tid - off] : 0;
        __syncthreads();
        s[tid] += t;
        __syncthreads();
    }
    int excl = s[tid] - v;
    bbase[tid] = excl;
    bcursor[tid] = excl;
    if (tid == NBUCK - 1) bbase[NBUCK] = N_EDGES_C;
}

__global__ __launch_bounds__(256) void k_scatter1(
    const int* __restrict__ src, const int* __restrict__ dst,
    int* __restrict__ bcursor, unsigned* __restrict__ tmp) {
    __shared__ int h[NBUCK], sc[NBUCK], gb[NBUCK], lc[NBUCK];
    __shared__ unsigned lbuf[CHUNK];
    const int tid = threadIdx.x;
    const int base = blockIdx.x * CHUNK;
    h[tid] = 0; lc[tid] = 0;
    __syncthreads();
    unsigned rec[EPT]; int bk[EPT];
#pragma unroll
    for (int i = 0; i < EPT; ++i) {
        int e = base + i * 256 + tid;
        if (e < N_EDGES_C) {
            int d = dst[e];
            int b = d / BSZ;
            rec[i] = ((unsigned)src[e] << 9) | (unsigned)(d - b * BSZ);
            bk[i] = b;
            atomicAdd(&h[b], 1);
        } else bk[i] = -1;
    }
    __syncthreads();
    int v = h[tid];
    sc[tid] = v;
    __syncthreads();
    for (int off = 1; off < NBUCK; off <<= 1) {
        int t = (tid >= off) ? sc[tid - off] : 0;
        __syncthreads();
        sc[tid] += t;
        __syncthreads();
    }
    int excl = sc[tid] - v;
    gb[tid] = v ? atomicAdd(&bcursor[tid], v) : 0;
    sc[tid] = excl;
    __syncthreads();
#pragma unroll
    for (int i = 0; i < EPT; ++i) {
        if (bk[i] >= 0) {
            int p = atomicAdd(&lc[bk[i]], 1);
            lbuf[sc[bk[i]] + p] = rec[i];
        }
    }
    __syncthreads();
    const int wid = tid >> 6, lane = tid & 63;
    for (int b = wid; b < NBUCK; b += 4) {
        int n = h[b], g = gb[b], l = sc[b];
        for (int i = lane; i < n; i += 64) tmp[g + i] = lbuf[l + i];
    }
}

__global__ __launch_bounds__(256) void k_sort2(
    const unsigned* __restrict__ tmp, const int* __restrict__ bbase,
    int* __restrict__ offsets, int* __restrict__ es) {
    __shared__ int h[512], s2[512], cur[512];
    __shared__ int lbuf[BCAP];
    const int b = blockIdx.x, tid = threadIdx.x;
    const int base = bbase[b];
    const int cnt = bbase[b + 1] - base;
    h[tid] = 0; h[tid + 256] = 0;
    __syncthreads();
    for (int i = tid; i < cnt; i += 256) atomicAdd(&h[tmp[base + i] & 511], 1);
    __syncthreads();
    int v0 = h[tid], v1 = h[tid + 256];
    s2[tid] = v0; s2[tid + 256] = v1;
    __syncthreads();
    for (int off = 1; off < 512; off <<= 1) {
        int t0 = (tid >= off) ? s2[tid - off] : 0;
        int t1 = (tid + 256 >= off) ? s2[tid + 256 - off] : 0;
        __syncthreads();
        s2[tid] += t0; s2[tid + 256] += t1;
        __syncthreads();
    }
    int e0 = s2[tid] - v0, e1 = s2[tid + 256] - v1;
    cur[tid] = e0; cur[tid + 256] = e1;
    {
        int gn0 = b * BSZ + tid;
        if (tid < BSZ && gn0 < N_NODES_C) offsets[gn0] = base + e0;
        int n1 = tid + 256;
        int gn1 = b * BSZ + n1;
        if (n1 < BSZ && gn1 < N_NODES_C) offsets[gn1] = base + e1;
    }
    __syncthreads();
    for (int i = tid; i < cnt; i += 256) {
        unsigned r = tmp[base + i];
        int ld = r & 511;
        int p = atomicAdd(&cur[ld], 1);
        lbuf[p] = (int)(r >> 9);
    }
    __syncthreads();
    for (int i = tid; i < cnt; i += 256) es[base + i] = lbuf[i];
    if (b == NBUCK - 1 && tid == 0) offsets[N_NODES_C] = N_EDGES_C;
}

// ==================== layers ====================

// Gather-sum: 16-lane group per node (f16x8=16B/lane). Confirmed at the
// random-row memory-system bound (~3.4 TB/s L2-miss; r21/r23 nulls).
__global__ __launch_bounds__(256) void k_gather(
    const _Float16* __restrict__ h_in, _Float16* __restrict__ agg,
    const int* __restrict__ offsets, const int* __restrict__ es) {
    const int node = (blockIdx.x << 4) + (threadIdx.x >> 4);  // 16 groups/block
    const int lane = threadIdx.x & 15;
    const int c8 = lane * 8;
    const int beg = offsets[node];
    const int end = offsets[node + 1];
    f32x8 a0 = {0.f, 0.f, 0.f, 0.f, 0.f, 0.f, 0.f, 0.f};
    f32x8 a1 = a0, a2 = a0, a3 = a0;
    int e = beg;
    for (; e + 8 <= end; e += 8) {
        int s0 = es[e],     s1 = es[e + 1], s2 = es[e + 2], s3 = es[e + 3];
        int s4 = es[e + 4], s5 = es[e + 5], s6 = es[e + 6], s7 = es[e + 7];
        f16x8 v0 = *(const f16x8*)(h_in + (size_t)s0 * HID + c8);
        f16x8 v1 = *(const f16x8*)(h_in + (size_t)s1 * HID + c8);
        f16x8 v2 = *(const f16x8*)(h_in + (size_t)s2 * HID + c8);
        f16x8 v3 = *(const f16x8*)(h_in + (size_t)s3 * HID + c8);
        f16x8 v4 = *(const f16x8*)(h_in + (size_t)s4 * HID + c8);
        f16x8 v5 = *(const f16x8*)(h_in + (size_t)s5 * HID + c8);
        f16x8 v6 = *(const f16x8*)(h_in + (size_t)s6 * HID + c8);
        f16x8 v7 = *(const f16x8*)(h_in + (size_t)s7 * HID + c8);
        a0 += h2f8(v0); a1 += h2f8(v1); a2 += h2f8(v2); a3 += h2f8(v3);
        a0 += h2f8(v4); a1 += h2f8(v5); a2 += h2f8(v6); a3 += h2f8(v7);
    }
    for (; e + 4 <= end; e += 4) {
        int s0 = es[e], s1 = es[e + 1], s2 = es[e + 2], s3 = es[e + 3];
        f16x8 v0 = *(const f16x8*)(h_in + (size_t)s0 * HID + c8);
        f16x8 v1 = *(const f16x8*)(h_in + (size_t)s1 * HID + c8);
        f16x8 v2 = *(const f16x8*)(h_in + (size_t)s2 * HID + c8);
        f16x8 v3 = *(const f16x8*)(h_in + (size_t)s3 * HID + c8);
        a0 += h2f8(v0); a1 += h2f8(v1); a2 += h2f8(v2); a3 += h2f8(v3);
    }
    for (; e < end; ++e)
        a0 += h2f8(*(const f16x8*)(h_in + (size_t)es[e] * HID + c8));
    f32x8 t = (a0 + a1) + (a2 + a3);
    *(f16x8*)(agg + (size_t)node * HID + c8) = __builtin_convertvector(t, f16x8);
}

// MFMA GEMM, LDS-staged (r21-confirmed transaction fix). GBLOCKS=512: 2
// resident blocks/CU so one block's MFMA overlaps the other's staging loads.
__global__ __launch_bounds__(256) void k_gemm_mfma(
    const _Float16* __restrict__ agg, const _Float16* __restrict__ h_in,
    _Float16* __restrict__ h_out,
    const _Float16* __restrict__ wT,   // [2][HID][HID] (j,k) for this layer
    const float* __restrict__ b_rel) {
    __shared__ _Float16 ldsA[GT * HID];  // 16 KB, seg-swizzled
    __shared__ _Float16 ldsH[GT * HID];  // 16 KB
    const int tid = threadIdx.x;
    const int lane = tid & 63;
    const int wv = tid >> 6;        // 0..3
    const int row16 = lane & 15;
    const int kg = lane >> 4;       // 0..3

    f16x8 WR[2][4], WO[2][4];
    float bb[2];
#pragma unroll
    for (int p = 0; p < 2; ++p) {
        const int j = ((2 * wv + p) << 4) + row16;
        const _Float16* wr = wT + (size_t)j * HID + (kg << 3);
        const _Float16* wo = wT + (size_t)(HID + j) * HID + (kg << 3);
#pragma unroll
        for (int s = 0; s < 4; ++s) {
            WR[p][s] = *(const f16x8*)(wr + s * 32);
            WO[p][s] = *(const f16x8*)(wo + s * 32);
        }
        bb[p] = b_rel[j];
    }

    for (int t = blockIdx.x; t < GTILES; t += GBLOCKS) {
        const int n0 = t * GT;
        __syncthreads();  // protect previous iteration's LDS reads
#pragma unroll
        for (int rnd = 0; rnd < 4; ++rnd) {
            const int idx = rnd * 256 + tid;  // 0..1023
            const int r = idx >> 4;           // row 0..63
            const int s = idx & 15;           // seg 0..15
            int n = n0 + r;
            if (n >= N_NODES_C) n = N_NODES_C - 1;  // clamp (stores guarded)
            const int sp = s ^ (r & 7);             // XOR swizzle
            *(f16x8*)(ldsA + ((size_t)r * 16 + sp) * 8) =
                *(const f16x8*)(agg + (size_t)n * HID + s * 8);
            *(f16x8*)(ldsH + ((size_t)r * 16 + sp) * 8) =
                *(const f16x8*)(h_in + (size_t)n * HID + s * 8);
        }
        __syncthreads();
#pragma unroll
        for (int p = 0; p < 2; ++p) {
            const int j = ((2 * wv + p) << 4) + row16;
#pragma unroll
            for (int nt = 0; nt < 4; ++nt) {
                const int r = nt * 16 + row16;  // A-row in tile
                f16x8 fA[4], fH[4];
#pragma unroll
                for (int s = 0; s < 4; ++s) {
                    const int sp = (s * 4 + kg) ^ (r & 7);
                    fA[s] = *(const f16x8*)(ldsA + ((size_t)r * 16 + sp) * 8);
                    fH[s] = *(const f16x8*)(ldsH + ((size_t)r * 16 + sp) * 8);
                }
                f32x4 a1 = {0.f, 0.f, 0.f, 0.f}, a2 = a1;
                a1 = __builtin_amdgcn_mfma_f32_16x16x32_f16(fA[0], WR[p][0], a1, 0, 0, 0);
                a2 = __builtin_amdgcn_mfma_f32_16x16x32_f16(fA[2], WR[p][2], a2, 0, 0, 0);
                a1 = __builtin_amdgcn_mfma_f32_16x16x32_f16(fH[0], WO[p][0], a1, 0, 0, 0);
                a2 = __builtin_amdgcn_mfma_f32_16x16x32_f16(fH[2], WO[p][2], a2, 0, 0, 0);
                a1 = __builtin_amdgcn_mfma_f32_16x16x32_f16(fA[1], WR[p][1], a1, 0, 0, 0);
                a2 = __builtin_amdgcn_mfma_f32_16x16x32_f16(fA[3], WR[p][3], a2, 0, 0, 0);
                a1 = __builtin_amdgcn_mfma_f32_16x16x32_f16(fH[1], WO[p][1], a1, 0, 0, 0);
                a2 = __builtin_amdgcn_mfma_f32_16x16x32_f16(fH[3], WO[p][3], a2, 0, 0, 0);
                const f32x4 acc = a1 + a2;
#pragma unroll
                for (int rr = 0; rr < 4; ++rr) {
                    const int n = n0 + nt * 16 + (kg << 2) + rr;
                    if (n < N_NODES_C)
                        h_out[(size_t)n * HID + j] = (_Float16)atanf(acc[rr] + bb[p]);
                }
            }
        }
    }
}

// Pool stage 1: per (graph, segment) partial sums over fp16 h -> fp32 part
__global__ __launch_bounds__(256) void k_pool1(
    const _Float16* __restrict__ h, const int* __restrict__ batch,
    float* __restrict__ part) {
    __shared__ float sm[2][HID];
    const int b = blockIdx.x;
    const int g = b >> 3, s = b & (SEG - 1);
    const int j = threadIdx.x & 127;
    const int half = threadIdx.x >> 7;

    int lo = 0, hi = N_NODES_C;
    while (lo < hi) { int mid = (lo + hi) >> 1; if (batch[mid] < g) lo = mid + 1; else hi = mid; }
    int start = lo;
    hi = N_NODES_C;
    while (lo < hi) { int mid = (lo + hi) >> 1; if (batch[mid] < g + 1) lo = mid + 1; else hi = mid; }
    int end = lo;
    int len = end - start;
    int s0 = start + (int)((long long)len * s / SEG);
    int s1 = start + (int)((long long)len * (s + 1) / SEG);

    float acc = 0.f;
    for (int i = s0 + half; i < s1; i += 2) acc += (float)h[(size_t)i * HID + j];
    sm[half][j] = acc;
    __syncthreads();
    if (threadIdx.x < HID) part[(size_t)b * HID + j] = sm[0][j] + sm[1][j];
}

// Pool stage 2 + head
__global__ __launch_bounds__(128) void k_head(
    const float* __restrict__ part, const float* __restrict__ W_out,
    const float* __restrict__ b_out, float* __restrict__ out) {
    __shared__ float sf[HID];
    const int g = blockIdx.x;
    const int j = threadIdx.x;
    float v = 0.f;
    for (int s = 0; s < SEG; ++s) v += part[(size_t)(g * SEG + s) * HID + j];
    sf[j] = v;
    __syncthreads();
    if (j < OUTD) {
        float a = b_out[j];
        for (int k = 0; k < HID; ++k) a += sf[k] * W_out[k * OUTD + j];
        out[g * OUTD + j] = 1.f / (1.f + expf(-a));
    }
}

extern "C" void kernel_launch(void* const* d_in, const int* in_sizes, int n_in,
                              void* d_out, int out_size, void* d_ws, size_t ws_size,
                              hipStream_t stream) {
    const float* x      = (const float*)d_in[0];
    const int*   ei     = (const int*)d_in[1];
    const int*   src    = ei;
    const int*   dst    = ei + N_EDGES_C;
    const int*   batch  = (const int*)d_in[2];
    const float* W_rel  = (const float*)d_in[3];
    const float* b_rel  = (const float*)d_in[4];
    const float* W_root = (const float*)d_in[5];
    const float* W_out  = (const float*)d_in[6];
    const float* b_out  = (const float*)d_in[7];
    float* out = (float*)d_out;

    char* ws = (char*)d_ws;
    size_t off = 0;
    auto alloc = [&](size_t bytes) { void* p = ws + off; off = align_up(off + bytes, 256); return p; };
    _Float16* xh    = (_Float16*)alloc((size_t)N_NODES_C * HID * 2);
    _Float16* h1h   = (_Float16*)alloc((size_t)N_NODES_C * HID * 2);
    _Float16* agg16 = (_Float16*)alloc((size_t)N_NODES_C * HID * 2);
    _Float16* wT    = (_Float16*)alloc((size_t)3 * 2 * HID * HID * 2);
    int*   offsets = (int*)alloc((size_t)(N_NODES_C + 1) * sizeof(int));
    int*   es      = (int*)alloc((size_t)N_EDGES_C * sizeof(int));
    unsigned* tmp  = (unsigned*)alloc((size_t)N_EDGES_C * sizeof(unsigned));
    int*   bhist   = (int*)alloc(NBUCK * sizeof(int));
    int*   bbase   = (int*)alloc((NBUCK + 1) * sizeof(int));
    int*   bcursor = (int*)alloc(NBUCK * sizeof(int));
    float* part    = (float*)alloc((size_t)N_GRAPHS_C * SEG * HID * sizeof(float));

    const int gather_blocks = N_NODES_C / 16;         // 6250
    const int scat_blocks = (N_EDGES_C + CHUNK - 1) / CHUNK;  // 391
    const size_t WTL = (size_t)2 * HID * HID;

    // ---- weight prep + x -> fp16 ----
    k_wprep<<<768, 128, 0, stream>>>(W_rel, W_root, wT);
    k_cvt<<<(N_NODES_C * HID) / 4 / 256, 256, 0, stream>>>(x, xh);

    // ---- CSR build: bucket sort, all global scatter staged through LDS ----
    k_zeroB<<<1, 256, 0, stream>>>(bhist);
    k_hist1<<<1024, 256, 0, stream>>>(dst, bhist);
    k_bscan<<<1, 256, 0, stream>>>(bhist, bbase, bcursor);
    k_scatter1<<<scat_blocks, 256, 0, stream>>>(src, dst, bcursor, tmp);
    k_sort2<<<NBUCK, 256, 0, stream>>>(tmp, bbase, offsets, es);

    // ---- 3 GraphConv layers: gather (split) + MFMA gemm (LDS-staged) ----
    k_gather<<<gather_blocks, 256, 0, stream>>>(xh, agg16, offsets, es);
    k_gemm_mfma<<<GBLOCKS, 256, 0, stream>>>(agg16, xh, h1h, wT + 0 * WTL, b_rel + 0 * HID);
    k_gather<<<gather_blocks, 256, 0, stream>>>(h1h, agg16, offsets, es);
    k_gemm_mfma<<<GBLOCKS, 256, 0, stream>>>(agg16, h1h, xh, wT + 1 * WTL, b_rel + 1 * HID);
    k_gather<<<gather_blocks, 256, 0, stream>>>(xh, agg16, offsets, es);
    k_gemm_mfma<<<GBLOCKS, 256, 0, stream>>>(agg16, xh, h1h, wT + 2 * WTL, b_rel + 2 * HID);

    // ---- pool + head ----
    k_pool1<<<N_GRAPHS_C * SEG, 256, 0, stream>>>(h1h, batch, part);
    k_head<<<N_GRAPHS_C, 128, 0, stream>>>(part, W_out, b_out, out);
}